// Round 1
// baseline (2779.839 us; speedup 1.0000x reference)
//
#include <hip/hip_runtime.h>

#define SEQ  1024
#define BATCH 8
#define NH   8
#define EMB  512
#define QHD  32
#define PHD  4
#define PDIM 192
#define NPROJ 544
#define NPE  2047   // 2*SEQ-1

// ---------------- Kernel A: pe_g[h*4+d][n] = (pos_emb @ W_pos)[n][h*4+d] ----------------
__global__ __launch_bounds__(256) void pe_kernel(const float* __restrict__ pos_emb,
                                                 const float* __restrict__ W_pos,
                                                 float* __restrict__ pe_g) {
    int n  = blockIdx.x * 64 + (threadIdx.x & 63);
    int hd = blockIdx.y * 4 + (threadIdx.x >> 6);
    if (n >= NPE) return;
    const float* pr = pos_emb + (size_t)n * PDIM;
    float acc = 0.f;
    for (int c = 0; c < PDIM; c += 4) {
        float4 pv = *(const float4*)(pr + c);
        acc += pv.x * W_pos[(c + 0) * 32 + hd];
        acc += pv.y * W_pos[(c + 1) * 32 + hd];
        acc += pv.z * W_pos[(c + 2) * 32 + hd];
        acc += pv.w * W_pos[(c + 3) * 32 + hd];
    }
    pe_g[hd * NPE + n] = acc;
}

// ---------------- Kernel B: xp = x @ W_in + b_in, scattered to q/k/p ----------------
// q_ws,k_ws: [H][B][S][32]; p_ws: [H][B][S][4]
__global__ __launch_bounds__(256) void inproj_kernel(const float* __restrict__ x,
                                                     const float* __restrict__ W,
                                                     const float* __restrict__ bias,
                                                     float* __restrict__ qws,
                                                     float* __restrict__ kws,
                                                     float* __restrict__ pws) {
    __shared__ float a_lds[16][68];
    __shared__ float b_lds[16][64];
    const int m0 = blockIdx.x * 64;
    const int n0 = blockIdx.y * 64;
    const int tn = threadIdx.x & 15, tm = threadIdx.x >> 4;
    const int mA = threadIdx.x >> 2, kqA = (threadIdx.x & 3) * 4;
    const int kB = threadIdx.x >> 4, nqB = (threadIdx.x & 15) * 4;
    float acc[4][4] = {};
    for (int k0 = 0; k0 < EMB; k0 += 16) {
        __syncthreads();
        float4 xa = *(const float4*)(x + (size_t)(m0 + mA) * EMB + k0 + kqA);
        float4 wb = make_float4(0.f, 0.f, 0.f, 0.f);
        if (n0 + nqB + 3 < NPROJ)
            wb = *(const float4*)(W + (size_t)(k0 + kB) * NPROJ + n0 + nqB);
        a_lds[kqA + 0][mA] = xa.x;
        a_lds[kqA + 1][mA] = xa.y;
        a_lds[kqA + 2][mA] = xa.z;
        a_lds[kqA + 3][mA] = xa.w;
        *(float4*)&b_lds[kB][nqB] = wb;
        __syncthreads();
#pragma unroll
        for (int k = 0; k < 16; ++k) {
            float4 a4 = *(const float4*)&a_lds[k][tm * 4];
            float4 b4 = *(const float4*)&b_lds[k][tn * 4];
            acc[0][0] += a4.x * b4.x; acc[0][1] += a4.x * b4.y; acc[0][2] += a4.x * b4.z; acc[0][3] += a4.x * b4.w;
            acc[1][0] += a4.y * b4.x; acc[1][1] += a4.y * b4.y; acc[1][2] += a4.y * b4.z; acc[1][3] += a4.y * b4.w;
            acc[2][0] += a4.z * b4.x; acc[2][1] += a4.z * b4.y; acc[2][2] += a4.z * b4.z; acc[2][3] += a4.z * b4.w;
            acc[3][0] += a4.w * b4.x; acc[3][1] += a4.w * b4.y; acc[3][2] += a4.w * b4.z; acc[3][3] += a4.w * b4.w;
        }
    }
    const int n = n0 + tn * 4;
    if (n >= NPROJ) return;
    float4 b4 = *(const float4*)(bias + n);
#pragma unroll
    for (int i = 0; i < 4; ++i) {
        int m = m0 + tm * 4 + i;
        int t = m >> 3, b = m & 7;
        float4 o;
        o.x = acc[i][0] + b4.x; o.y = acc[i][1] + b4.y; o.z = acc[i][2] + b4.z; o.w = acc[i][3] + b4.w;
        if (n < 256) {
            int h = n >> 5, d = n & 31;
            *(float4*)(qws + (((size_t)(h * 8 + b) * SEQ + t) * 32 + d)) = o;
        } else if (n < 512) {
            int nn = n - 256; int h = nn >> 5, d = nn & 31;
            *(float4*)(kws + (((size_t)(h * 8 + b) * SEQ + t) * 32 + d)) = o;
        } else {
            int nn = n - 512; int h = nn >> 2;
            *(float4*)(pws + ((size_t)(h * 8 + b) * SEQ + t) * 4) = o;
        }
    }
}

// ---------------- Kernel C: fused scores (content + shifted pos) + mask + softmax ----------------
__global__ __launch_bounds__(256, 1) void attn_kernel(const float* __restrict__ qws,
                                                      const float* __restrict__ kws,
                                                      const float* __restrict__ pws,
                                                      const float* __restrict__ pe_g,
                                                      const unsigned char* __restrict__ km,
                                                      float* __restrict__ out) {
    __shared__ float k_lds[32][SEQ];   // [d][s]  128 KB
    __shared__ float q_lds[128][32];   // 16 KB
    __shared__ float4 p_lds[128];      // 2 KB

    const int hb = blockIdx.y;
    const int h = hb >> 3, b = hb & 7;
    const int t0 = blockIdx.x * 128;
    const int tid = threadIdx.x, lane = tid & 63, w = tid >> 6;

    // stage k transposed: [d][s]
    const float* kbase = kws + (size_t)hb * SEQ * 32;
    {
        const int sK = tid & 63;
        const int dq4 = (tid >> 6) * 4;
#pragma unroll 4
        for (int it = 0; it < 32; ++it) {
            int c = it & 15, half = it >> 4;
            int s = c * 64 + sK;
            int d4 = dq4 + half * 16;
            float4 kv = *(const float4*)(kbase + (size_t)s * 32 + d4);
            k_lds[d4 + 0][s] = kv.x;
            k_lds[d4 + 1][s] = kv.y;
            k_lds[d4 + 2][s] = kv.z;
            k_lds[d4 + 3][s] = kv.w;
        }
    }
    // stage q (128 rows x 32)
    {
        const float* qbase = qws + ((size_t)hb * SEQ + t0) * 32;
#pragma unroll
        for (int r = 0; r < 4; ++r) {
            int idx = tid + 256 * r;
            int tq = idx >> 3, dq = (idx & 7) * 4;
            *(float4*)&q_lds[tq][dq] = *(const float4*)(qbase + tq * 32 + dq);
        }
    }
    if (tid < 128)
        p_lds[tid] = *(const float4*)(pws + ((size_t)hb * SEQ + t0 + tid) * 4);
    __syncthreads();

    const float* peh = pe_g + h * 4 * NPE;

    // mask words (same s-columns for every row this thread touches)
    unsigned int mw[4];
#pragma unroll
    for (int c = 0; c < 4; ++c)
        mw[c] = *(const unsigned int*)(km + b * SEQ + c * 256 + lane * 4);

#pragma unroll 1
    for (int pass = 0; pass < 4; ++pass) {
        const int tlbase = w * 32 + pass * 8;
        float acc[8][16];
#pragma unroll
        for (int r = 0; r < 8; ++r)
#pragma unroll
            for (int q = 0; q < 16; ++q) acc[r][q] = 0.f;

        // content scores: q . k
        for (int dq = 0; dq < 8; ++dq) {
            float qreg[8][4];
#pragma unroll
            for (int r = 0; r < 8; ++r) {
                float4 tq = *(const float4*)&q_lds[tlbase + r][dq * 4];
                qreg[r][0] = tq.x; qreg[r][1] = tq.y; qreg[r][2] = tq.z; qreg[r][3] = tq.w;
            }
#pragma unroll
            for (int dd = 0; dd < 4; ++dd) {
#pragma unroll
                for (int c = 0; c < 4; ++c) {
                    float4 kv = *(const float4*)&k_lds[dq * 4 + dd][c * 256 + lane * 4];
#pragma unroll
                    for (int r = 0; r < 8; ++r) {
                        acc[r][c * 4 + 0] += qreg[r][dd] * kv.x;
                        acc[r][c * 4 + 1] += qreg[r][dd] * kv.y;
                        acc[r][c * 4 + 2] += qreg[r][dd] * kv.z;
                        acc[r][c * 4 + 3] += qreg[r][dd] * kv.w;
                    }
                }
            }
        }

        // positional scores: shifted pe, n = (S-1) - t + s
#pragma unroll 1
        for (int r = 0; r < 8; ++r) {
            int t = t0 + tlbase + r;
            float4 pv = p_lds[tlbase + r];
            int nb = (SEQ - 1) - t;
#pragma unroll
            for (int c = 0; c < 4; ++c) {
                int n0 = nb + c * 256 + lane * 4;
#pragma unroll
                for (int j = 0; j < 4; ++j) {
                    const float* pp = peh + n0 + j;
                    float v = pp[0] * pv.x + pp[NPE] * pv.y + pp[2 * NPE] * pv.z + pp[3 * NPE] * pv.w;
                    acc[r][c * 4 + j] += v;
                }
            }
        }

        // mask + softmax + store
#pragma unroll 1
        for (int r = 0; r < 8; ++r) {
#pragma unroll
            for (int c = 0; c < 4; ++c) {
                unsigned int m = mw[c];
                if (m & 0x000000ffu) acc[r][c * 4 + 0] = -1000.f;
                if (m & 0x0000ff00u) acc[r][c * 4 + 1] = -1000.f;
                if (m & 0x00ff0000u) acc[r][c * 4 + 2] = -1000.f;
                if (m & 0xff000000u) acc[r][c * 4 + 3] = -1000.f;
            }
            float mx = acc[r][0];
#pragma unroll
            for (int q = 1; q < 16; ++q) mx = fmaxf(mx, acc[r][q]);
#pragma unroll
            for (int off = 32; off >= 1; off >>= 1) mx = fmaxf(mx, __shfl_xor(mx, off, 64));
            float sum = 0.f;
#pragma unroll
            for (int q = 0; q < 16; ++q) {
                acc[r][q] = __expf(acc[r][q] - mx);
                sum += acc[r][q];
            }
#pragma unroll
            for (int off = 32; off >= 1; off >>= 1) sum += __shfl_xor(sum, off, 64);
            float inv = 1.0f / sum;
            int t = t0 + tlbase + r;
            float* op = out + ((size_t)(hb * SEQ + t) << 10);
#pragma unroll
            for (int c = 0; c < 4; ++c) {
                float4 o;
                o.x = acc[r][c * 4 + 0] * inv;
                o.y = acc[r][c * 4 + 1] * inv;
                o.z = acc[r][c * 4 + 2] * inv;
                o.w = acc[r][c * 4 + 3] * inv;
                *(float4*)(op + c * 256 + lane * 4) = o;
            }
        }
    }
}

extern "C" void kernel_launch(void* const* d_in, const int* in_sizes, int n_in,
                              void* d_out, int out_size, void* d_ws, size_t ws_size,
                              hipStream_t stream) {
    const float* x       = (const float*)d_in[0];
    const float* pos_emb = (const float*)d_in[1];
    const float* W_in    = (const float*)d_in[2];
    const float* b_in    = (const float*)d_in[3];
    const float* W_pos   = (const float*)d_in[4];
    const unsigned char* km = (const unsigned char*)d_in[5];
    float* out = (float*)d_out;

    float* ws  = (float*)d_ws;
    float* qws = ws;                              // 2,097,152 floats
    float* kws = ws + (size_t)2097152;            // 2,097,152 floats
    float* pws = ws + (size_t)4194304;            // 262,144 floats
    float* peg = ws + (size_t)4456448;            // 65,504 floats

    hipLaunchKernelGGL(pe_kernel, dim3(32, 8), dim3(256), 0, stream, pos_emb, W_pos, peg);
    hipLaunchKernelGGL(inproj_kernel, dim3(128, 9), dim3(256), 0, stream, x, W_in, b_in, qws, kws, pws);
    hipLaunchKernelGGL(attn_kernel, dim3(8, 64), dim3(256), 0, stream, qws, kws, pws, peg, km, out);
}

// Round 2
// 1623.092 us; speedup vs baseline: 1.7127x; 1.7127x over previous
//
#include <hip/hip_runtime.h>

#define SEQ  1024
#define BATCH 8
#define NH   8
#define EMB  512
#define QHD  32
#define PHD  4
#define PDIM 192
#define NPROJ 544
#define NPE  2047   // 2*SEQ-1

typedef float nf4 __attribute__((ext_vector_type(4)));
struct __attribute__((packed, aligned(4))) F4u { float x, y, z, w; };  // align-4 float4 load

__device__ __forceinline__ float qcomp(const float4& v, int dd) {
    return dd == 0 ? v.x : dd == 1 ? v.y : dd == 2 ? v.z : v.w;
}

// ---------------- Kernel A: pe_g[h*4+d][n] = (pos_emb @ W_pos)[n][h*4+d] ----------------
__global__ __launch_bounds__(256) void pe_kernel(const float* __restrict__ pos_emb,
                                                 const float* __restrict__ W_pos,
                                                 float* __restrict__ pe_g) {
    int n  = blockIdx.x * 64 + (threadIdx.x & 63);
    int hd = blockIdx.y * 4 + (threadIdx.x >> 6);
    if (n >= NPE) return;
    const float* pr = pos_emb + (size_t)n * PDIM;
    float acc = 0.f;
    for (int c = 0; c < PDIM; c += 4) {
        float4 pv = *(const float4*)(pr + c);
        acc += pv.x * W_pos[(c + 0) * 32 + hd];
        acc += pv.y * W_pos[(c + 1) * 32 + hd];
        acc += pv.z * W_pos[(c + 2) * 32 + hd];
        acc += pv.w * W_pos[(c + 3) * 32 + hd];
    }
    pe_g[hd * NPE + n] = acc;
}

// ---------------- Kernel B: xp = x @ W_in + b_in, scattered to q/k/p ----------------
// q_ws,k_ws: [H*B][S][32]; p_ws: [H*B][S][4]
__global__ __launch_bounds__(256) void inproj_kernel(const float* __restrict__ x,
                                                     const float* __restrict__ W,
                                                     const float* __restrict__ bias,
                                                     float* __restrict__ qws,
                                                     float* __restrict__ kws,
                                                     float* __restrict__ pws) {
    __shared__ float a_lds[16][68];
    __shared__ float b_lds[16][64];
    const int m0 = blockIdx.x * 64;
    const int n0 = blockIdx.y * 64;
    const int tn = threadIdx.x & 15, tm = threadIdx.x >> 4;
    const int mA = threadIdx.x >> 2, kqA = (threadIdx.x & 3) * 4;
    const int kB = threadIdx.x >> 4, nqB = (threadIdx.x & 15) * 4;
    float acc[4][4] = {};
    for (int k0 = 0; k0 < EMB; k0 += 16) {
        __syncthreads();
        float4 xa = *(const float4*)(x + (size_t)(m0 + mA) * EMB + k0 + kqA);
        float4 wb = make_float4(0.f, 0.f, 0.f, 0.f);
        if (n0 + nqB + 3 < NPROJ)
            wb = *(const float4*)(W + (size_t)(k0 + kB) * NPROJ + n0 + nqB);
        a_lds[kqA + 0][mA] = xa.x;
        a_lds[kqA + 1][mA] = xa.y;
        a_lds[kqA + 2][mA] = xa.z;
        a_lds[kqA + 3][mA] = xa.w;
        *(float4*)&b_lds[kB][nqB] = wb;
        __syncthreads();
#pragma unroll
        for (int k = 0; k < 16; ++k) {
            float4 a4 = *(const float4*)&a_lds[k][tm * 4];
            float4 b4 = *(const float4*)&b_lds[k][tn * 4];
            acc[0][0] += a4.x * b4.x; acc[0][1] += a4.x * b4.y; acc[0][2] += a4.x * b4.z; acc[0][3] += a4.x * b4.w;
            acc[1][0] += a4.y * b4.x; acc[1][1] += a4.y * b4.y; acc[1][2] += a4.y * b4.z; acc[1][3] += a4.y * b4.w;
            acc[2][0] += a4.z * b4.x; acc[2][1] += a4.z * b4.y; acc[2][2] += a4.z * b4.z; acc[2][3] += a4.z * b4.w;
            acc[3][0] += a4.w * b4.x; acc[3][1] += a4.w * b4.y; acc[3][2] += a4.w * b4.z; acc[3][3] += a4.w * b4.w;
        }
    }
    const int n = n0 + tn * 4;
    if (n >= NPROJ) return;
    float4 b4 = *(const float4*)(bias + n);
#pragma unroll
    for (int i = 0; i < 4; ++i) {
        int m = m0 + tm * 4 + i;
        int t = m >> 3, b = m & 7;
        float4 o;
        o.x = acc[i][0] + b4.x; o.y = acc[i][1] + b4.y; o.z = acc[i][2] + b4.z; o.w = acc[i][3] + b4.w;
        if (n < 256) {
            int h = n >> 5, d = n & 31;
            *(float4*)(qws + (((size_t)(h * 8 + b) * SEQ + t) * 32 + d)) = o;
        } else if (n < 512) {
            int nn = n - 256; int h = nn >> 5, d = nn & 31;
            *(float4*)(kws + (((size_t)(h * 8 + b) * SEQ + t) * 32 + d)) = o;
        } else {
            int nn = n - 512; int h = nn >> 2;
            *(float4*)(pws + ((size_t)(h * 8 + b) * SEQ + t) * 4) = o;
        }
    }
}

// ---------------- Kernel C: fused scores (content + shifted pos) + mask + softmax ----------------
// 512 threads = 8 waves; block covers 64 t-rows x all 1024 s-cols.
// Wave w owns rows w*8..w*8+7; lane owns 16 s-cols (c*256 + lane*4 + j).
#define KPAD 1028
__global__ __launch_bounds__(512, 2) void attn_kernel(const float* __restrict__ qws,
                                                      const float* __restrict__ kws,
                                                      const float* __restrict__ pws,
                                                      const float* __restrict__ pe_g,
                                                      const unsigned char* __restrict__ km,
                                                      float* __restrict__ out) {
    __shared__ float k_lds[32][KPAD];  // [d][s], pad 4 -> 131.6 KB
    __shared__ float q_lds[64][32];    // 8 KB

    const int hb = blockIdx.y;
    const int h = hb >> 3, b = hb & 7;
    const int t0 = blockIdx.x * 64;
    const int tid = threadIdx.x, lane = tid & 63, w = tid >> 6;

    // ---- stage K transposed into LDS (coalesced global read) ----
    const float* kbase = kws + (size_t)hb * SEQ * 32;
#pragma unroll
    for (int it = 0; it < 16; ++it) {
        int idx = tid + 512 * it;
        int s = idx >> 3, d4 = (idx & 7) * 4;
        float4 kv = *(const float4*)(kbase + (size_t)s * 32 + d4);
        k_lds[d4 + 0][s] = kv.x;
        k_lds[d4 + 1][s] = kv.y;
        k_lds[d4 + 2][s] = kv.z;
        k_lds[d4 + 3][s] = kv.w;
    }
    // ---- stage Q rows t0..t0+63 ----
    {
        const float* qbase = qws + ((size_t)hb * SEQ + t0) * 32;
        int row = tid >> 3, d4 = (tid & 7) * 4;
        *(float4*)&q_lds[row][d4] = *(const float4*)(qbase + row * 32 + d4);
    }
    __syncthreads();

    // mask words for this lane's 16 columns
    unsigned int mw[4];
#pragma unroll
    for (int c = 0; c < 4; ++c)
        mw[c] = *(const unsigned int*)(km + b * SEQ + c * 256 + lane * 4);

    const int tl = w * 8;  // this wave's first local row
    float acc[8][16];
#pragma unroll
    for (int r = 0; r < 8; ++r)
#pragma unroll
        for (int q = 0; q < 16; ++q) acc[r][q] = 0.f;

    // ---- content scores: q . k ----
#pragma unroll 2
    for (int d4 = 0; d4 < 32; d4 += 4) {
        float4 qreg[8];
#pragma unroll
        for (int r = 0; r < 8; ++r) qreg[r] = *(const float4*)&q_lds[tl + r][d4];
#pragma unroll
        for (int dd = 0; dd < 4; ++dd) {
#pragma unroll
            for (int c = 0; c < 4; ++c) {
                float4 kv = *(const float4*)&k_lds[d4 + dd][c * 256 + lane * 4];
#pragma unroll
                for (int r = 0; r < 8; ++r) {
                    float q = qcomp(qreg[r], dd);
                    acc[r][c * 4 + 0] += q * kv.x;
                    acc[r][c * 4 + 1] += q * kv.y;
                    acc[r][c * 4 + 2] += q * kv.z;
                    acc[r][c * 4 + 3] += q * kv.w;
                }
            }
        }
    }

    // ---- positional scores: n = (S-1) - t + s ----
    const float* peh = pe_g + h * 4 * NPE;
#pragma unroll 1
    for (int r = 0; r < 8; ++r) {
        int t = t0 + tl + r;
        float4 pv = *(const float4*)(pws + ((size_t)hb * SEQ + t) * 4);  // broadcast
        const float* pp = peh + (SEQ - 1) - t;
#pragma unroll
        for (int c = 0; c < 4; ++c) {
            int n0 = c * 256 + lane * 4;
            F4u e0 = *(const F4u*)(pp + n0);
            F4u e1 = *(const F4u*)(pp + NPE + n0);
            F4u e2 = *(const F4u*)(pp + 2 * NPE + n0);
            F4u e3 = *(const F4u*)(pp + 3 * NPE + n0);
            acc[r][c * 4 + 0] += pv.x * e0.x + pv.y * e1.x + pv.z * e2.x + pv.w * e3.x;
            acc[r][c * 4 + 1] += pv.x * e0.y + pv.y * e1.y + pv.z * e2.y + pv.w * e3.y;
            acc[r][c * 4 + 2] += pv.x * e0.z + pv.y * e1.z + pv.z * e2.z + pv.w * e3.z;
            acc[r][c * 4 + 3] += pv.x * e0.w + pv.y * e1.w + pv.z * e2.w + pv.w * e3.w;
        }
    }

    // ---- mask + softmax + store ----
#pragma unroll 1
    for (int r = 0; r < 8; ++r) {
#pragma unroll
        for (int c = 0; c < 4; ++c) {
            unsigned int m = mw[c];
            if (m & 0x000000ffu) acc[r][c * 4 + 0] = -1000.f;
            if (m & 0x0000ff00u) acc[r][c * 4 + 1] = -1000.f;
            if (m & 0x00ff0000u) acc[r][c * 4 + 2] = -1000.f;
            if (m & 0xff000000u) acc[r][c * 4 + 3] = -1000.f;
        }
        float mx = acc[r][0];
#pragma unroll
        for (int q = 1; q < 16; ++q) mx = fmaxf(mx, acc[r][q]);
#pragma unroll
        for (int off = 32; off >= 1; off >>= 1) mx = fmaxf(mx, __shfl_xor(mx, off, 64));
        float sum = 0.f;
#pragma unroll
        for (int q = 0; q < 16; ++q) {
            acc[r][q] = __expf(acc[r][q] - mx);
            sum += acc[r][q];
        }
#pragma unroll
        for (int off = 32; off >= 1; off >>= 1) sum += __shfl_xor(sum, off, 64);
        float inv = 1.0f / sum;
        int t = t0 + tl + r;
        float* op = out + ((size_t)(hb * SEQ + t) << 10);
#pragma unroll
        for (int c = 0; c < 4; ++c) {
            nf4 o;
            o.x = acc[r][c * 4 + 0] * inv;
            o.y = acc[r][c * 4 + 1] * inv;
            o.z = acc[r][c * 4 + 2] * inv;
            o.w = acc[r][c * 4 + 3] * inv;
            __builtin_nontemporal_store(o, (nf4*)(op + c * 256 + lane * 4));
        }
    }
}

extern "C" void kernel_launch(void* const* d_in, const int* in_sizes, int n_in,
                              void* d_out, int out_size, void* d_ws, size_t ws_size,
                              hipStream_t stream) {
    const float* x       = (const float*)d_in[0];
    const float* pos_emb = (const float*)d_in[1];
    const float* W_in    = (const float*)d_in[2];
    const float* b_in    = (const float*)d_in[3];
    const float* W_pos   = (const float*)d_in[4];
    const unsigned char* km = (const unsigned char*)d_in[5];
    float* out = (float*)d_out;

    float* ws  = (float*)d_ws;
    float* qws = ws;                              // 2,097,152 floats
    float* kws = ws + (size_t)2097152;            // 2,097,152 floats
    float* pws = ws + (size_t)4194304;            // 262,144 floats
    float* peg = ws + (size_t)4456448;            // 65,504 floats

    hipLaunchKernelGGL(pe_kernel, dim3(32, 8), dim3(256), 0, stream, pos_emb, W_pos, peg);
    hipLaunchKernelGGL(inproj_kernel, dim3(128, 9), dim3(256), 0, stream, x, W_in, b_in, qws, kws, pws);
    hipLaunchKernelGGL(attn_kernel, dim3(16, 64), dim3(512), 0, stream, qws, kws, pws, peg, km, out);
}

// Round 3
// 453.381 us; speedup vs baseline: 6.1314x; 3.5800x over previous
//
#include <hip/hip_runtime.h>

#define SEQ  1024
#define BATCH 8
#define NH   8
#define EMB  512
#define QHD  32
#define PHD  4
#define PDIM 192
#define NPROJ 544
#define NPE  2047   // 2*SEQ-1

typedef float nf4 __attribute__((ext_vector_type(4)));
struct __attribute__((packed, aligned(4))) F4u { float x, y, z, w; };  // align-4 float4 load

__device__ __forceinline__ float qcomp(const float4& v, int dd) {
    return dd == 0 ? v.x : dd == 1 ? v.y : dd == 2 ? v.z : v.w;
}

// ---------------- Kernel A: pe_g[h*4+d][n] = (pos_emb @ W_pos)[n][h*4+d] ----------------
__global__ __launch_bounds__(256) void pe_kernel(const float* __restrict__ pos_emb,
                                                 const float* __restrict__ W_pos,
                                                 float* __restrict__ pe_g) {
    int n  = blockIdx.x * 64 + (threadIdx.x & 63);
    int hd = blockIdx.y * 4 + (threadIdx.x >> 6);
    if (n >= NPE) return;
    const float* pr = pos_emb + (size_t)n * PDIM;
    float acc = 0.f;
    for (int c = 0; c < PDIM; c += 4) {
        float4 pv = *(const float4*)(pr + c);
        acc += pv.x * W_pos[(c + 0) * 32 + hd];
        acc += pv.y * W_pos[(c + 1) * 32 + hd];
        acc += pv.z * W_pos[(c + 2) * 32 + hd];
        acc += pv.w * W_pos[(c + 3) * 32 + hd];
    }
    pe_g[hd * NPE + n] = acc;
}

// ---------------- Kernel B: xp = x @ W_in + b_in, scattered to q/k/p ----------------
// q_ws,k_ws: [H*B][S][32]; p_ws: [H*B][S][4]
__global__ __launch_bounds__(256) void inproj_kernel(const float* __restrict__ x,
                                                     const float* __restrict__ W,
                                                     const float* __restrict__ bias,
                                                     float* __restrict__ qws,
                                                     float* __restrict__ kws,
                                                     float* __restrict__ pws) {
    __shared__ float a_lds[16][68];
    __shared__ float b_lds[16][64];
    const int m0 = blockIdx.x * 64;
    const int n0 = blockIdx.y * 64;
    const int tn = threadIdx.x & 15, tm = threadIdx.x >> 4;
    const int mA = threadIdx.x >> 2, kqA = (threadIdx.x & 3) * 4;
    const int kB = threadIdx.x >> 4, nqB = (threadIdx.x & 15) * 4;
    float acc[4][4] = {};
    for (int k0 = 0; k0 < EMB; k0 += 16) {
        __syncthreads();
        float4 xa = *(const float4*)(x + (size_t)(m0 + mA) * EMB + k0 + kqA);
        float4 wb = make_float4(0.f, 0.f, 0.f, 0.f);
        if (n0 + nqB + 3 < NPROJ)
            wb = *(const float4*)(W + (size_t)(k0 + kB) * NPROJ + n0 + nqB);
        a_lds[kqA + 0][mA] = xa.x;
        a_lds[kqA + 1][mA] = xa.y;
        a_lds[kqA + 2][mA] = xa.z;
        a_lds[kqA + 3][mA] = xa.w;
        *(float4*)&b_lds[kB][nqB] = wb;
        __syncthreads();
#pragma unroll
        for (int k = 0; k < 16; ++k) {
            float4 a4 = *(const float4*)&a_lds[k][tm * 4];
            float4 b4 = *(const float4*)&b_lds[k][tn * 4];
            acc[0][0] += a4.x * b4.x; acc[0][1] += a4.x * b4.y; acc[0][2] += a4.x * b4.z; acc[0][3] += a4.x * b4.w;
            acc[1][0] += a4.y * b4.x; acc[1][1] += a4.y * b4.y; acc[1][2] += a4.y * b4.z; acc[1][3] += a4.y * b4.w;
            acc[2][0] += a4.z * b4.x; acc[2][1] += a4.z * b4.y; acc[2][2] += a4.z * b4.z; acc[2][3] += a4.z * b4.w;
            acc[3][0] += a4.w * b4.x; acc[3][1] += a4.w * b4.y; acc[3][2] += a4.w * b4.z; acc[3][3] += a4.w * b4.w;
        }
    }
    const int n = n0 + tn * 4;
    if (n >= NPROJ) return;
    float4 b4 = *(const float4*)(bias + n);
#pragma unroll
    for (int i = 0; i < 4; ++i) {
        int m = m0 + tm * 4 + i;
        int t = m >> 3, b = m & 7;
        float4 o;
        o.x = acc[i][0] + b4.x; o.y = acc[i][1] + b4.y; o.z = acc[i][2] + b4.z; o.w = acc[i][3] + b4.w;
        if (n < 256) {
            int h = n >> 5, d = n & 31;
            *(float4*)(qws + (((size_t)(h * 8 + b) * SEQ + t) * 32 + d)) = o;
        } else if (n < 512) {
            int nn = n - 256; int h = nn >> 5, d = nn & 31;
            *(float4*)(kws + (((size_t)(h * 8 + b) * SEQ + t) * 32 + d)) = o;
        } else {
            int nn = n - 512; int h = nn >> 2;
            *(float4*)(pws + ((size_t)(h * 8 + b) * SEQ + t) * 4) = o;
        }
    }
}

// ---------------- Kernel C: fused scores (content + shifted pos) + mask + softmax ----------------
// 512 threads = 8 waves; block covers 64 t-rows x all 1024 s-cols.
// Wave w owns rows w*8..w*8+7; lane owns 16 s-cols (c*256 + lane*4 + j).
// CRITICAL: every access to acc[][] must have compile-time indices (rule #20),
// otherwise the accumulator is demoted to scratch (R2: 8.4 GB of spill traffic).
#define KPAD 1028
__global__ __launch_bounds__(512, 2) void attn_kernel(const float* __restrict__ qws,
                                                      const float* __restrict__ kws,
                                                      const float* __restrict__ pws,
                                                      const float* __restrict__ pe_g,
                                                      const unsigned char* __restrict__ km,
                                                      float* __restrict__ out) {
    __shared__ float k_lds[32][KPAD];  // [d][s], pad 4 -> 131.6 KB
    __shared__ float q_lds[64][32];    // 8 KB

    const int hb = blockIdx.y;
    const int h = hb >> 3, b = hb & 7;
    const int t0 = blockIdx.x * 64;
    const int tid = threadIdx.x, lane = tid & 63, w = tid >> 6;

    // ---- stage K transposed into LDS (coalesced global read) ----
    const float* kbase = kws + (size_t)hb * SEQ * 32;
#pragma unroll
    for (int it = 0; it < 16; ++it) {
        int idx = tid + 512 * it;
        int s = idx >> 3, d4 = (idx & 7) * 4;
        float4 kv = *(const float4*)(kbase + (size_t)s * 32 + d4);
        k_lds[d4 + 0][s] = kv.x;
        k_lds[d4 + 1][s] = kv.y;
        k_lds[d4 + 2][s] = kv.z;
        k_lds[d4 + 3][s] = kv.w;
    }
    // ---- stage Q rows t0..t0+63 ----
    {
        const float* qbase = qws + ((size_t)hb * SEQ + t0) * 32;
        int row = tid >> 3, d4 = (tid & 7) * 4;
        *(float4*)&q_lds[row][d4] = *(const float4*)(qbase + row * 32 + d4);
    }
    __syncthreads();

    // mask words for this lane's 16 columns
    unsigned int mw[4];
#pragma unroll
    for (int c = 0; c < 4; ++c)
        mw[c] = *(const unsigned int*)(km + b * SEQ + c * 256 + lane * 4);

    const int tl = w * 8;  // this wave's first local row
    float acc[8][16];
#pragma unroll
    for (int r = 0; r < 8; ++r)
#pragma unroll
        for (int q = 0; q < 16; ++q) acc[r][q] = 0.f;

    // ---- content scores: q . k ----
#pragma unroll 2
    for (int d4 = 0; d4 < 32; d4 += 4) {
        float4 qreg[8];
#pragma unroll
        for (int r = 0; r < 8; ++r) qreg[r] = *(const float4*)&q_lds[tl + r][d4];
#pragma unroll
        for (int dd = 0; dd < 4; ++dd) {
#pragma unroll
            for (int c = 0; c < 4; ++c) {
                float4 kv = *(const float4*)&k_lds[d4 + dd][c * 256 + lane * 4];
#pragma unroll
                for (int r = 0; r < 8; ++r) {
                    float q = qcomp(qreg[r], dd);
                    acc[r][c * 4 + 0] += q * kv.x;
                    acc[r][c * 4 + 1] += q * kv.y;
                    acc[r][c * 4 + 2] += q * kv.z;
                    acc[r][c * 4 + 3] += q * kv.w;
                }
            }
        }
    }

    // ---- positional scores: n = (S-1) - t + s  (fully unrolled: static acc indices) ----
    const float* peh = pe_g + h * 4 * NPE;
#pragma unroll
    for (int r = 0; r < 8; ++r) {
        int t = t0 + tl + r;
        float4 pv = *(const float4*)(pws + ((size_t)hb * SEQ + t) * 4);  // broadcast
        const float* pp = peh + (SEQ - 1) - t;
#pragma unroll
        for (int c = 0; c < 4; ++c) {
            int n0 = c * 256 + lane * 4;
            F4u e0 = *(const F4u*)(pp + n0);
            F4u e1 = *(const F4u*)(pp + NPE + n0);
            F4u e2 = *(const F4u*)(pp + 2 * NPE + n0);
            F4u e3 = *(const F4u*)(pp + 3 * NPE + n0);
            acc[r][c * 4 + 0] += pv.x * e0.x + pv.y * e1.x + pv.z * e2.x + pv.w * e3.x;
            acc[r][c * 4 + 1] += pv.x * e0.y + pv.y * e1.y + pv.z * e2.y + pv.w * e3.y;
            acc[r][c * 4 + 2] += pv.x * e0.z + pv.y * e1.z + pv.z * e2.z + pv.w * e3.z;
            acc[r][c * 4 + 3] += pv.x * e0.w + pv.y * e1.w + pv.z * e2.w + pv.w * e3.w;
        }
    }

    // ---- mask + softmax + store (fully unrolled: static acc indices) ----
#pragma unroll
    for (int r = 0; r < 8; ++r) {
#pragma unroll
        for (int c = 0; c < 4; ++c) {
            unsigned int m = mw[c];
            if (m & 0x000000ffu) acc[r][c * 4 + 0] = -1000.f;
            if (m & 0x0000ff00u) acc[r][c * 4 + 1] = -1000.f;
            if (m & 0x00ff0000u) acc[r][c * 4 + 2] = -1000.f;
            if (m & 0xff000000u) acc[r][c * 4 + 3] = -1000.f;
        }
        float mx = acc[r][0];
#pragma unroll
        for (int q = 1; q < 16; ++q) mx = fmaxf(mx, acc[r][q]);
#pragma unroll
        for (int off = 32; off >= 1; off >>= 1) mx = fmaxf(mx, __shfl_xor(mx, off, 64));
        float sum = 0.f;
#pragma unroll
        for (int q = 0; q < 16; ++q) {
            acc[r][q] = __expf(acc[r][q] - mx);
            sum += acc[r][q];
        }
#pragma unroll
        for (int off = 32; off >= 1; off >>= 1) sum += __shfl_xor(sum, off, 64);
        float inv = 1.0f / sum;
        int t = t0 + tl + r;
        float* op = out + ((size_t)(hb * SEQ + t) << 10);
#pragma unroll
        for (int c = 0; c < 4; ++c) {
            nf4 o;
            o.x = acc[r][c * 4 + 0] * inv;
            o.y = acc[r][c * 4 + 1] * inv;
            o.z = acc[r][c * 4 + 2] * inv;
            o.w = acc[r][c * 4 + 3] * inv;
            __builtin_nontemporal_store(o, (nf4*)(op + c * 256 + lane * 4));
        }
    }
}

extern "C" void kernel_launch(void* const* d_in, const int* in_sizes, int n_in,
                              void* d_out, int out_size, void* d_ws, size_t ws_size,
                              hipStream_t stream) {
    const float* x       = (const float*)d_in[0];
    const float* pos_emb = (const float*)d_in[1];
    const float* W_in    = (const float*)d_in[2];
    const float* b_in    = (const float*)d_in[3];
    const float* W_pos   = (const float*)d_in[4];
    const unsigned char* km = (const unsigned char*)d_in[5];
    float* out = (float*)d_out;

    float* ws  = (float*)d_ws;
    float* qws = ws;                              // 2,097,152 floats
    float* kws = ws + (size_t)2097152;            // 2,097,152 floats
    float* pws = ws + (size_t)4194304;            // 262,144 floats
    float* peg = ws + (size_t)4456448;            // 65,504 floats

    hipLaunchKernelGGL(pe_kernel, dim3(32, 8), dim3(256), 0, stream, pos_emb, W_pos, peg);
    hipLaunchKernelGGL(inproj_kernel, dim3(128, 9), dim3(256), 0, stream, x, W_in, b_in, qws, kws, pws);
    hipLaunchKernelGGL(attn_kernel, dim3(16, 64), dim3(512), 0, stream, qws, kws, pws, peg, km, out);
}

// Round 4
// 215.085 us; speedup vs baseline: 12.9244x; 2.1079x over previous
//
#include <hip/hip_runtime.h>

#define SEQ  1024
#define BATCH 8
#define NH   8
#define EMB  512
#define QHD  32
#define PHD  4
#define PDIM 192
#define NPROJ 544
#define NPE  2047   // 2*SEQ-1
#define TBLK 32     // t-rows per attn block

typedef float nf4 __attribute__((ext_vector_type(4)));
typedef short bf16x8 __attribute__((ext_vector_type(8)));   // 8 bf16 in 4 VGPRs
typedef float f32x4 __attribute__((ext_vector_type(4)));

__device__ __forceinline__ unsigned short f2bf_rne(float f) {
    unsigned int u = __float_as_uint(f);
    unsigned int r = (u + 0x7fffu + ((u >> 16) & 1u)) >> 16;
    return (unsigned short)r;
}
__device__ __forceinline__ float bf2f(unsigned short b) {
    return __uint_as_float(((unsigned int)b) << 16);
}

// ---------------- Kernel A: pe_g[h*4+d][n] = (pos_emb @ W_pos)[n][h*4+d] ----------------
__global__ __launch_bounds__(256) void pe_kernel(const float* __restrict__ pos_emb,
                                                 const float* __restrict__ W_pos,
                                                 float* __restrict__ pe_g) {
    int n  = blockIdx.x * 64 + (threadIdx.x & 63);
    int hd = blockIdx.y * 4 + (threadIdx.x >> 6);
    if (n >= NPE) return;
    const float* pr = pos_emb + (size_t)n * PDIM;
    float acc = 0.f;
    for (int c = 0; c < PDIM; c += 4) {
        float4 pv = *(const float4*)(pr + c);
        acc += pv.x * W_pos[(c + 0) * 32 + hd];
        acc += pv.y * W_pos[(c + 1) * 32 + hd];
        acc += pv.z * W_pos[(c + 2) * 32 + hd];
        acc += pv.w * W_pos[(c + 3) * 32 + hd];
    }
    pe_g[hd * NPE + n] = acc;
}

// ---------------- Kernel B: xp = x @ W_in + b_in -> q/k as bf16 hi/lo, p fp32 ----------------
// qhi/qlo/khi/klo: [H*B][S][32] bf16(ushort); pws: [H*B][S][4] fp32
__global__ __launch_bounds__(256) void inproj_kernel(const float* __restrict__ x,
                                                     const float* __restrict__ W,
                                                     const float* __restrict__ bias,
                                                     unsigned short* __restrict__ qhi,
                                                     unsigned short* __restrict__ qlo,
                                                     unsigned short* __restrict__ khi,
                                                     unsigned short* __restrict__ klo,
                                                     float* __restrict__ pws) {
    __shared__ float a_lds[16][68];
    __shared__ float b_lds[16][64];
    const int m0 = blockIdx.x * 64;
    const int n0 = blockIdx.y * 64;
    const int tn = threadIdx.x & 15, tm = threadIdx.x >> 4;
    const int mA = threadIdx.x >> 2, kqA = (threadIdx.x & 3) * 4;
    const int kB = threadIdx.x >> 4, nqB = (threadIdx.x & 15) * 4;
    float acc[4][4] = {};
    for (int k0 = 0; k0 < EMB; k0 += 16) {
        __syncthreads();
        float4 xa = *(const float4*)(x + (size_t)(m0 + mA) * EMB + k0 + kqA);
        float4 wb = make_float4(0.f, 0.f, 0.f, 0.f);
        if (n0 + nqB + 3 < NPROJ)
            wb = *(const float4*)(W + (size_t)(k0 + kB) * NPROJ + n0 + nqB);
        a_lds[kqA + 0][mA] = xa.x;
        a_lds[kqA + 1][mA] = xa.y;
        a_lds[kqA + 2][mA] = xa.z;
        a_lds[kqA + 3][mA] = xa.w;
        *(float4*)&b_lds[kB][nqB] = wb;
        __syncthreads();
#pragma unroll
        for (int k = 0; k < 16; ++k) {
            float4 a4 = *(const float4*)&a_lds[k][tm * 4];
            float4 b4 = *(const float4*)&b_lds[k][tn * 4];
            acc[0][0] += a4.x * b4.x; acc[0][1] += a4.x * b4.y; acc[0][2] += a4.x * b4.z; acc[0][3] += a4.x * b4.w;
            acc[1][0] += a4.y * b4.x; acc[1][1] += a4.y * b4.y; acc[1][2] += a4.y * b4.z; acc[1][3] += a4.y * b4.w;
            acc[2][0] += a4.z * b4.x; acc[2][1] += a4.z * b4.y; acc[2][2] += a4.z * b4.z; acc[2][3] += a4.z * b4.w;
            acc[3][0] += a4.w * b4.x; acc[3][1] += a4.w * b4.y; acc[3][2] += a4.w * b4.z; acc[3][3] += a4.w * b4.w;
        }
    }
    const int n = n0 + tn * 4;
    if (n >= NPROJ) return;
    float4 b4 = *(const float4*)(bias + n);
#pragma unroll
    for (int i = 0; i < 4; ++i) {
        int m = m0 + tm * 4 + i;
        int t = m >> 3, b = m & 7;
        float v[4];
        v[0] = acc[i][0] + b4.x; v[1] = acc[i][1] + b4.y; v[2] = acc[i][2] + b4.z; v[3] = acc[i][3] + b4.w;
        if (n < 512) {
            int nn = (n < 256) ? n : n - 256;
            int h = nn >> 5, d = nn & 31;
            size_t base = ((size_t)(h * 8 + b) * SEQ + t) * 32 + d;
            ushort4 hi, lo;
            unsigned short h0 = f2bf_rne(v[0]); hi.x = h0; lo.x = f2bf_rne(v[0] - bf2f(h0));
            unsigned short h1 = f2bf_rne(v[1]); hi.y = h1; lo.y = f2bf_rne(v[1] - bf2f(h1));
            unsigned short h2 = f2bf_rne(v[2]); hi.z = h2; lo.z = f2bf_rne(v[2] - bf2f(h2));
            unsigned short h3 = f2bf_rne(v[3]); hi.w = h3; lo.w = f2bf_rne(v[3] - bf2f(h3));
            if (n < 256) {
                *(ushort4*)(qhi + base) = hi;
                *(ushort4*)(qlo + base) = lo;
            } else {
                *(ushort4*)(khi + base) = hi;
                *(ushort4*)(klo + base) = lo;
            }
        } else {
            int nn = n - 512; int h = nn >> 2;
            float4 o; o.x = v[0]; o.y = v[1]; o.z = v[2]; o.w = v[3];
            *(float4*)(pws + ((size_t)(h * 8 + b) * SEQ + t) * 4) = o;
        }
    }
}

// ---------------- Kernel C: MFMA scores (bf16x3) + shifted pos + mask + softmax ----------------
// 512 threads = 8 waves. Block: 32 t-rows x 1024 s-cols for one (h,b).
// Wave w: t-tile i=w>>2 (16 rows), s-chunk j=w&3 (256 cols = 16 MFMA tiles).
// Computes C'[s][t] = K.Q^T so each lane owns ONE t (col=lane&15) and
// 64 s-values in 16 groups of 4 consecutive (row=(lane>>4)*4+reg).
__global__ __launch_bounds__(512, 1) void attn_kernel(const unsigned short* __restrict__ qhi,
                                                      const unsigned short* __restrict__ qlo,
                                                      const unsigned short* __restrict__ khi,
                                                      const unsigned short* __restrict__ klo,
                                                      const float* __restrict__ pws,
                                                      const float* __restrict__ pe_g,
                                                      const unsigned char* __restrict__ km,
                                                      float* __restrict__ out) {
    __shared__ __align__(16) unsigned short khi_lds[SEQ * 32];  // 64 KB
    __shared__ __align__(16) unsigned short klo_lds[SEQ * 32];  // 64 KB
    __shared__ float pe_lds[4][1056];                           // 16.9 KB
    __shared__ float red_m[2][16][4];
    __shared__ float red_s[2][16][4];

    const int hb = blockIdx.y;
    const int h = hb >> 3, b = hb & 7;
    const int t0 = blockIdx.x * TBLK;
    const int tid = threadIdx.x, lane = tid & 63, w = tid >> 6;
    const int la = lane & 15, lb = lane >> 4;
    const int i_t = w >> 2, j_s = w & 3;

    // ---- stage K hi/lo into LDS (linear [s][32] bf16; 16B per lane per iter) ----
    const unsigned short* ghi = khi + (size_t)hb * (SEQ * 32);
    const unsigned short* glo = klo + (size_t)hb * (SEQ * 32);
#pragma unroll
    for (int it = 0; it < 8; ++it) {
        int idx = it * 512 + tid;          // 16B chunk index
        uint4 a = *(const uint4*)(ghi + idx * 8);
        uint4 c = *(const uint4*)(glo + idx * 8);
        *(uint4*)(khi_lds + idx * 8) = a;
        *(uint4*)(klo_lds + idx * 8) = c;
    }
    // ---- stage pe window: pe_lds[d][o] = peg[h*4+d][nbase+o], o in [0,1055) ----
    const int nbase = SEQ - 1 - t0 - (TBLK - 1);
#pragma unroll
    for (int it = 0; it < 9; ++it) {
        int idx = it * 512 + tid;
        if (idx < 4 * 1056) {
            int d = idx / 1056, o = idx - d * 1056;
            float v = 0.f;
            if (o < 1055) v = pe_g[(h * 4 + d) * NPE + nbase + o];
            pe_lds[d][o] = v;
        }
    }
    __syncthreads();

    // ---- Q B-fragments (direct from global, 16B/lane) ----
    const int t_local = i_t * 16 + la;
    const int t = t0 + t_local;
    const size_t qoff = ((size_t)hb * SEQ + t) * 32 + lb * 8;
    const bf16x8 bqh = *(const bf16x8*)(qhi + qoff);
    const bf16x8 bql = *(const bf16x8*)(qlo + qoff);

    // ---- content scores via MFMA: acc[m] covers s = j_s*256 + m*16 + lb*4 + {0..3} ----
    f32x4 acc[16];
#pragma unroll
    for (int m = 0; m < 16; ++m) acc[m] = (f32x4){0.f, 0.f, 0.f, 0.f};

#pragma unroll
    for (int m = 0; m < 16; ++m) {
        const int srow = j_s * 256 + m * 16 + la;
        const bf16x8 ah = *(const bf16x8*)(khi_lds + srow * 32 + lb * 8);
        const bf16x8 al = *(const bf16x8*)(klo_lds + srow * 32 + lb * 8);
        acc[m] = __builtin_amdgcn_mfma_f32_16x16x32_bf16(ah, bqh, acc[m], 0, 0, 0);
        acc[m] = __builtin_amdgcn_mfma_f32_16x16x32_bf16(ah, bql, acc[m], 0, 0, 0);
        acc[m] = __builtin_amdgcn_mfma_f32_16x16x32_bf16(al, bqh, acc[m], 0, 0, 0);
    }

    // ---- positional scores: idx into pe_lds = s + 31 - t_local ----
    const float4 pvv = *(const float4*)(pws + ((size_t)hb * SEQ + t) * 4);
    const float pv[4] = {pvv.x, pvv.y, pvv.z, pvv.w};
    const int lane_off = j_s * 256 + lb * 4 + (TBLK - 1) - t_local;
#pragma unroll
    for (int m = 0; m < 16; ++m) {
        const int o = lane_off + m * 16;
#pragma unroll
        for (int d = 0; d < 4; ++d) {
            acc[m][0] += pv[d] * pe_lds[d][o + 0];
            acc[m][1] += pv[d] * pe_lds[d][o + 1];
            acc[m][2] += pv[d] * pe_lds[d][o + 2];
            acc[m][3] += pv[d] * pe_lds[d][o + 3];
        }
    }

    // ---- key padding mask ----
    const unsigned int* kmw = (const unsigned int*)(km + b * SEQ);
#pragma unroll
    for (int m = 0; m < 16; ++m) {
        unsigned int mk = kmw[(j_s * 256 + m * 16 + lb * 4) >> 2];
        if (mk & 0x000000ffu) acc[m][0] = -1000.f;
        if (mk & 0x0000ff00u) acc[m][1] = -1000.f;
        if (mk & 0x00ff0000u) acc[m][2] = -1000.f;
        if (mk & 0xff000000u) acc[m][3] = -1000.f;
    }

    // ---- softmax over s (per t-row) ----
    float mx = -3.4e38f;
#pragma unroll
    for (int m = 0; m < 16; ++m) {
        mx = fmaxf(mx, fmaxf(fmaxf(acc[m][0], acc[m][1]), fmaxf(acc[m][2], acc[m][3])));
    }
    mx = fmaxf(mx, __shfl_xor(mx, 16, 64));
    mx = fmaxf(mx, __shfl_xor(mx, 32, 64));
    if (lane < 16) red_m[i_t][lane][j_s] = mx;
    __syncthreads();
    const float fm = fmaxf(fmaxf(red_m[i_t][la][0], red_m[i_t][la][1]),
                           fmaxf(red_m[i_t][la][2], red_m[i_t][la][3]));
    float sum = 0.f;
#pragma unroll
    for (int m = 0; m < 16; ++m) {
        acc[m][0] = __expf(acc[m][0] - fm);
        acc[m][1] = __expf(acc[m][1] - fm);
        acc[m][2] = __expf(acc[m][2] - fm);
        acc[m][3] = __expf(acc[m][3] - fm);
        sum += (acc[m][0] + acc[m][1]) + (acc[m][2] + acc[m][3]);
    }
    sum += __shfl_xor(sum, 16, 64);
    sum += __shfl_xor(sum, 32, 64);
    if (lane < 16) red_s[i_t][lane][j_s] = sum;
    __syncthreads();
    const float fs = (red_s[i_t][la][0] + red_s[i_t][la][1]) +
                     (red_s[i_t][la][2] + red_s[i_t][la][3]);
    const float inv = 1.0f / fs;

    // ---- store: per m one 16B chunk; 4 lanes (lb=0..3) cover 64B contiguous ----
    float* op = out + ((size_t)hb * SEQ + t) * SEQ;
#pragma unroll
    for (int m = 0; m < 16; ++m) {
        nf4 o;
        o.x = acc[m][0] * inv;
        o.y = acc[m][1] * inv;
        o.z = acc[m][2] * inv;
        o.w = acc[m][3] * inv;
        __builtin_nontemporal_store(o, (nf4*)(op + j_s * 256 + m * 16 + lb * 4));
    }
}

extern "C" void kernel_launch(void* const* d_in, const int* in_sizes, int n_in,
                              void* d_out, int out_size, void* d_ws, size_t ws_size,
                              hipStream_t stream) {
    const float* x       = (const float*)d_in[0];
    const float* pos_emb = (const float*)d_in[1];
    const float* W_in    = (const float*)d_in[2];
    const float* b_in    = (const float*)d_in[3];
    const float* W_pos   = (const float*)d_in[4];
    const unsigned char* km = (const unsigned char*)d_in[5];
    float* out = (float*)d_out;

    char* ws = (char*)d_ws;
    const size_t QK = (size_t)64 * SEQ * 32 * 2;  // 4 MB each
    unsigned short* qhi = (unsigned short*)(ws);
    unsigned short* qlo = (unsigned short*)(ws + QK);
    unsigned short* khi = (unsigned short*)(ws + 2 * QK);
    unsigned short* klo = (unsigned short*)(ws + 3 * QK);
    float* pws = (float*)(ws + 4 * QK);                        // 1 MB
    float* peg = (float*)(ws + 4 * QK + (size_t)1048576);      // 256 KB

    hipLaunchKernelGGL(pe_kernel, dim3(32, 8), dim3(256), 0, stream, pos_emb, W_pos, peg);
    hipLaunchKernelGGL(inproj_kernel, dim3(128, 9), dim3(256), 0, stream,
                       x, W_in, b_in, qhi, qlo, khi, klo, pws);
    hipLaunchKernelGGL(attn_kernel, dim3(SEQ / TBLK, 64), dim3(512), 0, stream,
                       qhi, qlo, khi, klo, pws, peg, km, out);
}

// Round 5
// 173.989 us; speedup vs baseline: 15.9771x; 1.2362x over previous
//
#include <hip/hip_runtime.h>

#define SEQ  1024
#define BATCH 8
#define NH   8
#define EMB  512
#define QHD  32
#define PHD  4
#define PDIM 192
#define NPROJ 544
#define NPE  2047   // 2*SEQ-1
#define TBLK 64     // t-rows per attn block

typedef float nf4 __attribute__((ext_vector_type(4)));
typedef short bf16x8 __attribute__((ext_vector_type(8)));   // 8 bf16 in 4 VGPRs
typedef float f32x4 __attribute__((ext_vector_type(4)));

__device__ __forceinline__ unsigned short f2bf_rne(float f) {
    unsigned int u = __float_as_uint(f);
    unsigned int r = (u + 0x7fffu + ((u >> 16) & 1u)) >> 16;
    return (unsigned short)r;
}
__device__ __forceinline__ float bf2f(unsigned short b) {
    return __uint_as_float(((unsigned int)b) << 16);
}

// ---------------- Kernel X: x (fp32) -> xhi/xlo (bf16), row-major [8192][512] ----------------
__global__ __launch_bounds__(256) void convx_kernel(const float* __restrict__ x,
                                                    unsigned short* __restrict__ xhi,
                                                    unsigned short* __restrict__ xlo) {
    int i = (blockIdx.x * 256 + threadIdx.x) * 8;
    float4 a = *(const float4*)(x + i);
    float4 b = *(const float4*)(x + i + 4);
    ushort4 h0, l0, h1, l1;
    h0.x = f2bf_rne(a.x); l0.x = f2bf_rne(a.x - bf2f(h0.x));
    h0.y = f2bf_rne(a.y); l0.y = f2bf_rne(a.y - bf2f(h0.y));
    h0.z = f2bf_rne(a.z); l0.z = f2bf_rne(a.z - bf2f(h0.z));
    h0.w = f2bf_rne(a.w); l0.w = f2bf_rne(a.w - bf2f(h0.w));
    h1.x = f2bf_rne(b.x); l1.x = f2bf_rne(b.x - bf2f(h1.x));
    h1.y = f2bf_rne(b.y); l1.y = f2bf_rne(b.y - bf2f(h1.y));
    h1.z = f2bf_rne(b.z); l1.z = f2bf_rne(b.z - bf2f(h1.z));
    h1.w = f2bf_rne(b.w); l1.w = f2bf_rne(b.w - bf2f(h1.w));
    *(ushort4*)(xhi + i) = h0; *(ushort4*)(xhi + i + 4) = h1;
    *(ushort4*)(xlo + i) = l0; *(ushort4*)(xlo + i + 4) = l1;
}

// ---------------- Kernel W: W_in (fp32 [512][544]) -> whT/wlT (bf16 [544][512]) ----------------
__global__ __launch_bounds__(256) void convw_kernel(const float* __restrict__ W,
                                                    unsigned short* __restrict__ whT,
                                                    unsigned short* __restrict__ wlT) {
    __shared__ float tile[32][33];
    const int n0 = blockIdx.x * 32, k0 = blockIdx.y * 32;
    const int c = threadIdx.x & 31, r0 = threadIdx.x >> 5;
#pragma unroll
    for (int i = 0; i < 4; ++i) {
        int r = r0 + i * 8;
        tile[r][c] = W[(size_t)(k0 + r) * NPROJ + n0 + c];
    }
    __syncthreads();
#pragma unroll
    for (int i = 0; i < 4; ++i) {
        int n = r0 + i * 8;
        float v = tile[c][n];
        unsigned short h = f2bf_rne(v);
        unsigned short l = f2bf_rne(v - bf2f(h));
        whT[(size_t)(n0 + n) * 512 + k0 + c] = h;
        wlT[(size_t)(n0 + n) * 512 + k0 + c] = l;
    }
}

// ---------------- Kernel A: pe_g[h*4+d][n] = (pos_emb @ W_pos)[n][h*4+d] ----------------
__global__ __launch_bounds__(256) void pe_kernel(const float* __restrict__ pos_emb,
                                                 const float* __restrict__ W_pos,
                                                 float* __restrict__ pe_g) {
    int n  = blockIdx.x * 64 + (threadIdx.x & 63);
    int hd = blockIdx.y * 4 + (threadIdx.x >> 6);
    if (n >= NPE) return;
    const float* pr = pos_emb + (size_t)n * PDIM;
    float acc = 0.f;
    for (int c = 0; c < PDIM; c += 4) {
        float4 pv = *(const float4*)(pr + c);
        acc += pv.x * W_pos[(c + 0) * 32 + hd];
        acc += pv.y * W_pos[(c + 1) * 32 + hd];
        acc += pv.z * W_pos[(c + 2) * 32 + hd];
        acc += pv.w * W_pos[(c + 3) * 32 + hd];
    }
    pe_g[hd * NPE + n] = acc;
}

// ---------------- Kernel B: MFMA in-proj (bf16x3): xp = x @ W_in + b_in ----------------
// Block 256 thr (4 waves), tile M=128 x N=32, K-step 64 (8 steps).
// C'[n][m]: lane col = m (la), rows n = lb*4+reg (+16*nt). Wave w owns m rows w*32..+31.
// LDS subtiled [k8][m][8] so frag ds_read_b128 is conflict-free.
__global__ __launch_bounds__(256) void inproj_kernel(const unsigned short* __restrict__ xhi,
                                                     const unsigned short* __restrict__ xlo,
                                                     const unsigned short* __restrict__ whT,
                                                     const unsigned short* __restrict__ wlT,
                                                     const float* __restrict__ bias,
                                                     unsigned short* __restrict__ qhi,
                                                     unsigned short* __restrict__ qlo,
                                                     unsigned short* __restrict__ khi,
                                                     unsigned short* __restrict__ klo,
                                                     float* __restrict__ pws) {
    __shared__ __align__(16) unsigned short xh_l[8][128][8];  // 16 KB
    __shared__ __align__(16) unsigned short xl_l[8][128][8];  // 16 KB
    __shared__ __align__(16) unsigned short wh_l[8][32][8];   // 4 KB
    __shared__ __align__(16) unsigned short wl_l[8][32][8];   // 4 KB

    const int tid = threadIdx.x, lane = tid & 63, w = tid >> 6;
    const int la = lane & 15, lb = lane >> 4;
    const int m0 = blockIdx.x * 128, n0 = blockIdx.y * 32;

    // staging indices (constant across K-steps)
    const int mx = tid >> 1, k8x = (tid & 1) * 4;   // x: 4 chunks: (k8x+j, mx)
    const int nw = tid >> 3, k8w = tid & 7;         // w: 1 chunk

    f32x4 acc[2][2];
#pragma unroll
    for (int mt = 0; mt < 2; ++mt)
#pragma unroll
        for (int nt = 0; nt < 2; ++nt) acc[mt][nt] = (f32x4){0.f, 0.f, 0.f, 0.f};

    for (int step = 0; step < 8; ++step) {
        const int k0 = step * 64;
        const unsigned short* sxh = xhi + (size_t)(m0 + mx) * 512 + k0 + k8x * 8;
        const unsigned short* sxl = xlo + (size_t)(m0 + mx) * 512 + k0 + k8x * 8;
#pragma unroll
        for (int j = 0; j < 4; ++j) {
            *(uint4*)&xh_l[k8x + j][mx][0] = *(const uint4*)(sxh + j * 8);
            *(uint4*)&xl_l[k8x + j][mx][0] = *(const uint4*)(sxl + j * 8);
        }
        *(uint4*)&wh_l[k8w][nw][0] = *(const uint4*)(whT + (size_t)(n0 + nw) * 512 + k0 + k8w * 8);
        *(uint4*)&wl_l[k8w][nw][0] = *(const uint4*)(wlT + (size_t)(n0 + nw) * 512 + k0 + k8w * 8);
        __syncthreads();
#pragma unroll
        for (int ks = 0; ks < 2; ++ks) {
            bf16x8 bh[2], bl[2], ah[2], al[2];
#pragma unroll
            for (int mt = 0; mt < 2; ++mt) {
                bh[mt] = *(const bf16x8*)&xh_l[ks * 4 + lb][w * 32 + mt * 16 + la][0];
                bl[mt] = *(const bf16x8*)&xl_l[ks * 4 + lb][w * 32 + mt * 16 + la][0];
            }
#pragma unroll
            for (int nt = 0; nt < 2; ++nt) {
                ah[nt] = *(const bf16x8*)&wh_l[ks * 4 + lb][nt * 16 + la][0];
                al[nt] = *(const bf16x8*)&wl_l[ks * 4 + lb][nt * 16 + la][0];
            }
#pragma unroll
            for (int mt = 0; mt < 2; ++mt)
#pragma unroll
                for (int nt = 0; nt < 2; ++nt) {
                    acc[mt][nt] = __builtin_amdgcn_mfma_f32_16x16x32_bf16(ah[nt], bh[mt], acc[mt][nt], 0, 0, 0);
                    acc[mt][nt] = __builtin_amdgcn_mfma_f32_16x16x32_bf16(ah[nt], bl[mt], acc[mt][nt], 0, 0, 0);
                    acc[mt][nt] = __builtin_amdgcn_mfma_f32_16x16x32_bf16(al[nt], bh[mt], acc[mt][nt], 0, 0, 0);
                }
        }
        __syncthreads();
    }

    // epilogue: n = n0 + nt*16 + lb*4 + r; m = m0 + w*32 + mt*16 + la
    const int by = blockIdx.y;
#pragma unroll
    for (int mt = 0; mt < 2; ++mt) {
        const int m = m0 + w * 32 + mt * 16 + la;
        const int s = m >> 3, bb = m & 7;
#pragma unroll
        for (int nt = 0; nt < 2; ++nt) {
            const int dloc = nt * 16 + lb * 4;
            float4 b4 = *(const float4*)(bias + n0 + dloc);
            float v0 = acc[mt][nt][0] + b4.x;
            float v1 = acc[mt][nt][1] + b4.y;
            float v2 = acc[mt][nt][2] + b4.z;
            float v3 = acc[mt][nt][3] + b4.w;
            if (by < 16) {
                const int h = by & 7;
                size_t base = (((size_t)(h * 8 + bb) * SEQ + s) * 32 + dloc);
                ushort4 hi, lo;
                hi.x = f2bf_rne(v0); lo.x = f2bf_rne(v0 - bf2f(hi.x));
                hi.y = f2bf_rne(v1); lo.y = f2bf_rne(v1 - bf2f(hi.y));
                hi.z = f2bf_rne(v2); lo.z = f2bf_rne(v2 - bf2f(hi.z));
                hi.w = f2bf_rne(v3); lo.w = f2bf_rne(v3 - bf2f(hi.w));
                if (by < 8) {
                    *(ushort4*)(qhi + base) = hi;
                    *(ushort4*)(qlo + base) = lo;
                } else {
                    *(ushort4*)(khi + base) = hi;
                    *(ushort4*)(klo + base) = lo;
                }
            } else {
                const int h = nt * 4 + lb;  // (n-512)>>2
                float4 o; o.x = v0; o.y = v1; o.z = v2; o.w = v3;
                *(float4*)(pws + ((size_t)(h * 8 + bb) * SEQ + s) * 4) = o;
            }
        }
    }
}

// ---------------- Kernel C: MFMA scores (bf16x3) + shifted pos + mask + softmax ----------------
// 512 threads = 8 waves. Block: 64 t-rows x 1024 s-cols for one (h,b).
// Wave w: t-tile i_t=w>>1 (16 rows), s-half j_s=w&1 (512 cols = 32 MFMA tiles).
// C'[s][t] = K.Q^T: lane owns ONE t (la) and 128 s-values (32 groups of 4).
__global__ __launch_bounds__(512, 1) void attn_kernel(const unsigned short* __restrict__ qhi,
                                                      const unsigned short* __restrict__ qlo,
                                                      const unsigned short* __restrict__ khi,
                                                      const unsigned short* __restrict__ klo,
                                                      const float* __restrict__ pws,
                                                      const float* __restrict__ pe_g,
                                                      const unsigned char* __restrict__ km,
                                                      float* __restrict__ out) {
    __shared__ __align__(16) unsigned short khi_lds[SEQ * 32];  // 64 KB
    __shared__ __align__(16) unsigned short klo_lds[SEQ * 32];  // 64 KB
    __shared__ __align__(16) float pe4_lds[1088][4];            // 17 KB
    __shared__ float red_m[4][16][2];
    __shared__ float red_s[4][16][2];

    const int hb = blockIdx.y;
    const int h = hb >> 3, b = hb & 7;
    const int t0 = blockIdx.x * TBLK;
    const int tid = threadIdx.x, lane = tid & 63, w = tid >> 6;
    const int la = lane & 15, lb = lane >> 4;
    const int i_t = w >> 1, j_s = w & 1;

    // ---- stage K hi/lo into LDS (linear [s][32] bf16) ----
    const unsigned short* ghi = khi + (size_t)hb * (SEQ * 32);
    const unsigned short* glo = klo + (size_t)hb * (SEQ * 32);
#pragma unroll
    for (int it = 0; it < 8; ++it) {
        int idx = it * 512 + tid;
        uint4 a = *(const uint4*)(ghi + idx * 8);
        uint4 c = *(const uint4*)(glo + idx * 8);
        *(uint4*)(khi_lds + idx * 8) = a;
        *(uint4*)(klo_lds + idx * 8) = c;
    }
    // ---- stage pe window: pe4_lds[o][d] = peg[h*4+d][nbase+o], o in [0,1087) ----
    const int nbase = SEQ - 1 - t0 - (TBLK - 1);
#pragma unroll
    for (int it = 0; it < 9; ++it) {
        int idx = it * 512 + tid;
        if (idx < 4 * 1088) {
            int d = idx / 1088, o = idx - d * 1088;
            float v = 0.f;
            if (o < 1087) v = pe_g[(h * 4 + d) * NPE + nbase + o];
            pe4_lds[o][d] = v;
        }
    }
    __syncthreads();

    // ---- Q B-fragments (direct from global) ----
    const int t_local = i_t * 16 + la;
    const int t = t0 + t_local;
    const size_t qoff = ((size_t)hb * SEQ + t) * 32 + lb * 8;
    const bf16x8 bqh = *(const bf16x8*)(qhi + qoff);
    const bf16x8 bql = *(const bf16x8*)(qlo + qoff);

    // ---- content scores: acc[m] covers s = j_s*512 + m*16 + lb*4 + {0..3} ----
    f32x4 acc[32];
#pragma unroll
    for (int m = 0; m < 32; ++m) acc[m] = (f32x4){0.f, 0.f, 0.f, 0.f};

#pragma unroll
    for (int m = 0; m < 32; ++m) {
        const int srow = j_s * 512 + m * 16 + la;
        const bf16x8 ah = *(const bf16x8*)(khi_lds + srow * 32 + lb * 8);
        const bf16x8 al = *(const bf16x8*)(klo_lds + srow * 32 + lb * 8);
        acc[m] = __builtin_amdgcn_mfma_f32_16x16x32_bf16(ah, bqh, acc[m], 0, 0, 0);
        acc[m] = __builtin_amdgcn_mfma_f32_16x16x32_bf16(ah, bql, acc[m], 0, 0, 0);
        acc[m] = __builtin_amdgcn_mfma_f32_16x16x32_bf16(al, bqh, acc[m], 0, 0, 0);
    }

    // ---- positional scores: pe4[o][0..3] dot p ----
    const float4 pvv = *(const float4*)(pws + ((size_t)hb * SEQ + t) * 4);
    const int lane_off = j_s * 512 + lb * 4 + (TBLK - 1) - t_local;
#pragma unroll
    for (int m = 0; m < 32; ++m) {
        const int o = lane_off + m * 16;
#pragma unroll
        for (int j = 0; j < 4; ++j) {
            float4 e = *(const float4*)&pe4_lds[o + j][0];
            acc[m][j] += pvv.x * e.x + pvv.y * e.y + pvv.z * e.z + pvv.w * e.w;
        }
    }

    // ---- key padding mask ----
    const unsigned int* kmw = (const unsigned int*)(km + b * SEQ);
#pragma unroll
    for (int m = 0; m < 32; ++m) {
        unsigned int mk = kmw[j_s * 128 + m * 4 + lb];
        if (mk & 0x000000ffu) acc[m][0] = -1000.f;
        if (mk & 0x0000ff00u) acc[m][1] = -1000.f;
        if (mk & 0x00ff0000u) acc[m][2] = -1000.f;
        if (mk & 0xff000000u) acc[m][3] = -1000.f;
    }

    // ---- softmax over s (per t-row) ----
    float mx = -3.4e38f;
#pragma unroll
    for (int m = 0; m < 32; ++m)
        mx = fmaxf(mx, fmaxf(fmaxf(acc[m][0], acc[m][1]), fmaxf(acc[m][2], acc[m][3])));
    mx = fmaxf(mx, __shfl_xor(mx, 16, 64));
    mx = fmaxf(mx, __shfl_xor(mx, 32, 64));
    if (lane < 16) red_m[i_t][lane][j_s] = mx;
    __syncthreads();
    const float fm = fmaxf(red_m[i_t][la][0], red_m[i_t][la][1]);
    float sum = 0.f;
#pragma unroll
    for (int m = 0; m < 32; ++m) {
        acc[m][0] = __expf(acc[m][0] - fm);
        acc[m][1] = __expf(acc[m][1] - fm);
        acc[m][2] = __expf(acc[m][2] - fm);
        acc[m][3] = __expf(acc[m][3] - fm);
        sum += (acc[m][0] + acc[m][1]) + (acc[m][2] + acc[m][3]);
    }
    sum += __shfl_xor(sum, 16, 64);
    sum += __shfl_xor(sum, 32, 64);
    if (lane < 16) red_s[i_t][lane][j_s] = sum;
    __syncthreads();
    const float inv = 1.0f / (red_s[i_t][la][0] + red_s[i_t][la][1]);

    // ---- store ----
    float* op = out + ((size_t)hb * SEQ + t) * SEQ;
#pragma unroll
    for (int m = 0; m < 32; ++m) {
        nf4 o;
        o.x = acc[m][0] * inv;
        o.y = acc[m][1] * inv;
        o.z = acc[m][2] * inv;
        o.w = acc[m][3] * inv;
        __builtin_nontemporal_store(o, (nf4*)(op + j_s * 512 + m * 16 + lb * 4));
    }
}

extern "C" void kernel_launch(void* const* d_in, const int* in_sizes, int n_in,
                              void* d_out, int out_size, void* d_ws, size_t ws_size,
                              hipStream_t stream) {
    const float* x       = (const float*)d_in[0];
    const float* pos_emb = (const float*)d_in[1];
    const float* W_in    = (const float*)d_in[2];
    const float* b_in    = (const float*)d_in[3];
    const float* W_pos   = (const float*)d_in[4];
    const unsigned char* km = (const unsigned char*)d_in[5];
    float* out = (float*)d_out;

    char* ws = (char*)d_ws;
    const size_t MB = 1024 * 1024;
    unsigned short* qhi = (unsigned short*)(ws);
    unsigned short* qlo = (unsigned short*)(ws + 4 * MB);
    unsigned short* khi = (unsigned short*)(ws + 8 * MB);
    unsigned short* klo = (unsigned short*)(ws + 12 * MB);
    float*          pws = (float*)(ws + 16 * MB);
    float*          peg = (float*)(ws + 17 * MB);
    unsigned short* xhi = (unsigned short*)(ws + 18 * MB);
    unsigned short* xlo = (unsigned short*)(ws + 26 * MB);
    unsigned short* whT = (unsigned short*)(ws + 34 * MB);
    unsigned short* wlT = (unsigned short*)(ws + 35 * MB);

    hipLaunchKernelGGL(convx_kernel, dim3(2048), dim3(256), 0, stream, x, xhi, xlo);
    hipLaunchKernelGGL(convw_kernel, dim3(17, 16), dim3(256), 0, stream, W_in, whT, wlT);
    hipLaunchKernelGGL(pe_kernel, dim3(32, 8), dim3(256), 0, stream, pos_emb, W_pos, peg);
    hipLaunchKernelGGL(inproj_kernel, dim3(64, 17), dim3(256), 0, stream,
                       xhi, xlo, whT, wlT, b_in, qhi, qlo, khi, klo, pws);
    hipLaunchKernelGGL(attn_kernel, dim3(SEQ / TBLK, 64), dim3(512), 0, stream,
                       qhi, qlo, khi, klo, pws, peg, km, out);
}

// Round 6
// 160.339 us; speedup vs baseline: 17.3372x; 1.0851x over previous
//
#include <hip/hip_runtime.h>

#define SEQ  1024
#define BATCH 8
#define NH   8
#define EMB  512
#define QHD  32
#define PHD  4
#define PDIM 192
#define NPROJ 544
#define NPE  2047   // 2*SEQ-1

typedef float nf4 __attribute__((ext_vector_type(4)));
typedef short bf16x8 __attribute__((ext_vector_type(8)));   // 8 bf16 in 4 VGPRs
typedef float f32x4 __attribute__((ext_vector_type(4)));

__device__ __forceinline__ unsigned short f2bf_rne(float f) {
    unsigned int u = __float_as_uint(f);
    unsigned int r = (u + 0x7fffu + ((u >> 16) & 1u)) >> 16;
    return (unsigned short)r;
}
__device__ __forceinline__ float bf2f(unsigned short b) {
    return __uint_as_float(((unsigned int)b) << 16);
}

// ---------------- Kernel X: x (fp32) -> xhi/xlo (bf16), row-major [8192][512] ----------------
__global__ __launch_bounds__(256) void convx_kernel(const float* __restrict__ x,
                                                    unsigned short* __restrict__ xhi,
                                                    unsigned short* __restrict__ xlo) {
    int i = (blockIdx.x * 256 + threadIdx.x) * 8;
    float4 a = *(const float4*)(x + i);
    float4 b = *(const float4*)(x + i + 4);
    ushort4 h0, l0, h1, l1;
    h0.x = f2bf_rne(a.x); l0.x = f2bf_rne(a.x - bf2f(h0.x));
    h0.y = f2bf_rne(a.y); l0.y = f2bf_rne(a.y - bf2f(h0.y));
    h0.z = f2bf_rne(a.z); l0.z = f2bf_rne(a.z - bf2f(h0.z));
    h0.w = f2bf_rne(a.w); l0.w = f2bf_rne(a.w - bf2f(h0.w));
    h1.x = f2bf_rne(b.x); l1.x = f2bf_rne(b.x - bf2f(h1.x));
    h1.y = f2bf_rne(b.y); l1.y = f2bf_rne(b.y - bf2f(h1.y));
    h1.z = f2bf_rne(b.z); l1.z = f2bf_rne(b.z - bf2f(h1.z));
    h1.w = f2bf_rne(b.w); l1.w = f2bf_rne(b.w - bf2f(h1.w));
    *(ushort4*)(xhi + i) = h0; *(ushort4*)(xhi + i + 4) = h1;
    *(ushort4*)(xlo + i) = l0; *(ushort4*)(xlo + i + 4) = l1;
}

// ---------------- Kernel W: W_in (fp32 [512][544]) -> whT/wlT (bf16 [544][512]) ----------------
__global__ __launch_bounds__(256) void convw_kernel(const float* __restrict__ W,
                                                    unsigned short* __restrict__ whT,
                                                    unsigned short* __restrict__ wlT) {
    __shared__ float tile[32][33];
    const int n0 = blockIdx.x * 32, k0 = blockIdx.y * 32;
    const int c = threadIdx.x & 31, r0 = threadIdx.x >> 5;
#pragma unroll
    for (int i = 0; i < 4; ++i) {
        int r = r0 + i * 8;
        tile[r][c] = W[(size_t)(k0 + r) * NPROJ + n0 + c];
    }
    __syncthreads();
#pragma unroll
    for (int i = 0; i < 4; ++i) {
        int n = r0 + i * 8;
        float v = tile[c][n];
        unsigned short h = f2bf_rne(v);
        unsigned short l = f2bf_rne(v - bf2f(h));
        whT[(size_t)(n0 + n) * 512 + k0 + c] = h;
        wlT[(size_t)(n0 + n) * 512 + k0 + c] = l;
    }
}

// ---------------- Kernel A: peg_bf[h][n] = ushort4 bf16 of (pos_emb @ W_pos)[n][h*4+0..3] ----
__global__ __launch_bounds__(128) void pe_kernel(const float* __restrict__ pos_emb,
                                                 const float* __restrict__ W_pos,
                                                 unsigned short* __restrict__ peg) {
    const int n = blockIdx.x * 128 + threadIdx.x;
    const int h = blockIdx.y;
    if (n >= NPE) return;
    const float* pr = pos_emb + (size_t)n * PDIM;
    float a0 = 0.f, a1 = 0.f, a2 = 0.f, a3 = 0.f;
    for (int c = 0; c < PDIM; c += 4) {
        float4 pv = *(const float4*)(pr + c);
#pragma unroll
        for (int cc = 0; cc < 4; ++cc) {
            float pvc = cc == 0 ? pv.x : cc == 1 ? pv.y : cc == 2 ? pv.z : pv.w;
            float4 w4 = *(const float4*)(W_pos + (c + cc) * 32 + h * 4);
            a0 += pvc * w4.x; a1 += pvc * w4.y; a2 += pvc * w4.z; a3 += pvc * w4.w;
        }
    }
    ushort4 o;
    o.x = f2bf_rne(a0); o.y = f2bf_rne(a1); o.z = f2bf_rne(a2); o.w = f2bf_rne(a3);
    *(ushort4*)(peg + ((size_t)h * NPE + n) * 4) = o;
}

// ---------------- Kernel B: MFMA in-proj (bf16x3): xp = x @ W_in + b_in ----------------
__global__ __launch_bounds__(256) void inproj_kernel(const unsigned short* __restrict__ xhi,
                                                     const unsigned short* __restrict__ xlo,
                                                     const unsigned short* __restrict__ whT,
                                                     const unsigned short* __restrict__ wlT,
                                                     const float* __restrict__ bias,
                                                     unsigned short* __restrict__ qhi,
                                                     unsigned short* __restrict__ qlo,
                                                     unsigned short* __restrict__ khi,
                                                     unsigned short* __restrict__ klo,
                                                     float* __restrict__ pws) {
    __shared__ __align__(16) unsigned short xh_l[8][128][8];  // 16 KB
    __shared__ __align__(16) unsigned short xl_l[8][128][8];  // 16 KB
    __shared__ __align__(16) unsigned short wh_l[8][32][8];   // 4 KB
    __shared__ __align__(16) unsigned short wl_l[8][32][8];   // 4 KB

    const int tid = threadIdx.x, lane = tid & 63, w = tid >> 6;
    const int la = lane & 15, lb = lane >> 4;
    const int m0 = blockIdx.x * 128, n0 = blockIdx.y * 32;

    const int mx = tid >> 1, k8x = (tid & 1) * 4;
    const int nw = tid >> 3, k8w = tid & 7;

    f32x4 acc[2][2];
#pragma unroll
    for (int mt = 0; mt < 2; ++mt)
#pragma unroll
        for (int nt = 0; nt < 2; ++nt) acc[mt][nt] = (f32x4){0.f, 0.f, 0.f, 0.f};

    for (int step = 0; step < 8; ++step) {
        const int k0 = step * 64;
        const unsigned short* sxh = xhi + (size_t)(m0 + mx) * 512 + k0 + k8x * 8;
        const unsigned short* sxl = xlo + (size_t)(m0 + mx) * 512 + k0 + k8x * 8;
#pragma unroll
        for (int j = 0; j < 4; ++j) {
            *(uint4*)&xh_l[k8x + j][mx][0] = *(const uint4*)(sxh + j * 8);
            *(uint4*)&xl_l[k8x + j][mx][0] = *(const uint4*)(sxl + j * 8);
        }
        *(uint4*)&wh_l[k8w][nw][0] = *(const uint4*)(whT + (size_t)(n0 + nw) * 512 + k0 + k8w * 8);
        *(uint4*)&wl_l[k8w][nw][0] = *(const uint4*)(wlT + (size_t)(n0 + nw) * 512 + k0 + k8w * 8);
        __syncthreads();
#pragma unroll
        for (int ks = 0; ks < 2; ++ks) {
            bf16x8 bh[2], bl[2], ah[2], al[2];
#pragma unroll
            for (int mt = 0; mt < 2; ++mt) {
                bh[mt] = *(const bf16x8*)&xh_l[ks * 4 + lb][w * 32 + mt * 16 + la][0];
                bl[mt] = *(const bf16x8*)&xl_l[ks * 4 + lb][w * 32 + mt * 16 + la][0];
            }
#pragma unroll
            for (int nt = 0; nt < 2; ++nt) {
                ah[nt] = *(const bf16x8*)&wh_l[ks * 4 + lb][nt * 16 + la][0];
                al[nt] = *(const bf16x8*)&wl_l[ks * 4 + lb][nt * 16 + la][0];
            }
#pragma unroll
            for (int mt = 0; mt < 2; ++mt)
#pragma unroll
                for (int nt = 0; nt < 2; ++nt) {
                    acc[mt][nt] = __builtin_amdgcn_mfma_f32_16x16x32_bf16(ah[nt], bh[mt], acc[mt][nt], 0, 0, 0);
                    acc[mt][nt] = __builtin_amdgcn_mfma_f32_16x16x32_bf16(ah[nt], bl[mt], acc[mt][nt], 0, 0, 0);
                    acc[mt][nt] = __builtin_amdgcn_mfma_f32_16x16x32_bf16(al[nt], bh[mt], acc[mt][nt], 0, 0, 0);
                }
        }
        __syncthreads();
    }

    const int by = blockIdx.y;
#pragma unroll
    for (int mt = 0; mt < 2; ++mt) {
        const int m = m0 + w * 32 + mt * 16 + la;
        const int s = m >> 3, bb = m & 7;
#pragma unroll
        for (int nt = 0; nt < 2; ++nt) {
            const int dloc = nt * 16 + lb * 4;
            float4 b4 = *(const float4*)(bias + n0 + dloc);
            float v0 = acc[mt][nt][0] + b4.x;
            float v1 = acc[mt][nt][1] + b4.y;
            float v2 = acc[mt][nt][2] + b4.z;
            float v3 = acc[mt][nt][3] + b4.w;
            if (by < 16) {
                const int h = by & 7;
                size_t base = (((size_t)(h * 8 + bb) * SEQ + s) * 32 + dloc);
                ushort4 hi, lo;
                hi.x = f2bf_rne(v0); lo.x = f2bf_rne(v0 - bf2f(hi.x));
                hi.y = f2bf_rne(v1); lo.y = f2bf_rne(v1 - bf2f(hi.y));
                hi.z = f2bf_rne(v2); lo.z = f2bf_rne(v2 - bf2f(hi.z));
                hi.w = f2bf_rne(v3); lo.w = f2bf_rne(v3 - bf2f(hi.w));
                if (by < 8) {
                    *(ushort4*)(qhi + base) = hi;
                    *(ushort4*)(qlo + base) = lo;
                } else {
                    *(ushort4*)(khi + base) = hi;
                    *(ushort4*)(klo + base) = lo;
                }
            } else {
                const int h = nt * 4 + lb;
                float4 o; o.x = v0; o.y = v1; o.z = v2; o.w = v3;
                *(float4*)(pws + ((size_t)(h * 8 + bb) * SEQ + s) * 4) = o;
            }
        }
    }
}

// ---------------- Kernel C: MFMA scores, K-frags from global (L2), pe bf16 in LDS ----------
// 256 threads = 4 waves; block = 16 t-rows x 1024 s for one (h,b).
// Wave j_s owns s-chunk [j_s*256, +256). C'[s][t]: lane la = t-col, rows s = lb*4+reg.
// Grid 1-D 4096: hb = bid & 63 (keeps same-KV blocks on one XCD), t0 = (bid>>6)*16.
__global__ __launch_bounds__(256, 3) void attn_kernel(const unsigned short* __restrict__ qhi,
                                                      const unsigned short* __restrict__ qlo,
                                                      const unsigned short* __restrict__ khi,
                                                      const unsigned short* __restrict__ klo,
                                                      const float* __restrict__ pws,
                                                      const unsigned short* __restrict__ peg,
                                                      const unsigned char* __restrict__ km,
                                                      float* __restrict__ out) {
    __shared__ unsigned long long pe_lds[1040];  // 8.3 KB: slot o = 4 bf16 (d0..d3)
    __shared__ float red_m[16][4];
    __shared__ float red_s[16][4];

    const int bid = blockIdx.x;
    const int hb = bid & 63;
    const int h = hb >> 3, b = hb & 7;
    const int t0 = (bid >> 6) * 16;
    const int tid = threadIdx.x, lane = tid & 63;
    const int j_s = tid >> 6;
    const int la = lane & 15, lb = lane >> 4;

    // ---- stage pe band (bf16, 1039 slots); nbase in [0,1008], no bounds issues ----
    const int nbase = (SEQ - 1) - t0 - 15;
    const unsigned long long* pegq = (const unsigned long long*)peg + (size_t)h * NPE + nbase;
#pragma unroll
    for (int it = 0; it < 5; ++it) {
        int idx = it * 256 + tid;
        if (idx < 1039) pe_lds[idx] = pegq[idx];
    }
    __syncthreads();

    // ---- Q B-fragments ----
    const int t = t0 + la;
    const size_t qoff = ((size_t)hb * SEQ + t) * 32 + lb * 8;
    const bf16x8 bqh = *(const bf16x8*)(qhi + qoff);
    const bf16x8 bql = *(const bf16x8*)(qlo + qoff);

    const unsigned short* khb = khi + (size_t)hb * (SEQ * 32);
    const unsigned short* klb = klo + (size_t)hb * (SEQ * 32);

    // ---- content scores: K-frags straight from global (coalesced, L2-hot) ----
    f32x4 acc[16];
#pragma unroll
    for (int m = 0; m < 16; ++m) acc[m] = (f32x4){0.f, 0.f, 0.f, 0.f};

#pragma unroll
    for (int m = 0; m < 16; ++m) {
        const int srow = j_s * 256 + m * 16 + la;
        const bf16x8 ah = *(const bf16x8*)(khb + (size_t)srow * 32 + lb * 8);
        const bf16x8 al = *(const bf16x8*)(klb + (size_t)srow * 32 + lb * 8);
        acc[m] = __builtin_amdgcn_mfma_f32_16x16x32_bf16(ah, bqh, acc[m], 0, 0, 0);
        acc[m] = __builtin_amdgcn_mfma_f32_16x16x32_bf16(ah, bql, acc[m], 0, 0, 0);
        acc[m] = __builtin_amdgcn_mfma_f32_16x16x32_bf16(al, bqh, acc[m], 0, 0, 0);
    }

    // ---- positional scores from bf16 pe_lds: o = s + 15 - t_local ----
    const float4 pvv = *(const float4*)(pws + ((size_t)hb * SEQ + t) * 4);
    const int lane_off = j_s * 256 + lb * 4 + 15 - la;
#pragma unroll
    for (int m = 0; m < 16; ++m) {
        const int o = lane_off + m * 16;
#pragma unroll
        for (int j = 0; j < 4; ++j) {
            unsigned long long v = pe_lds[o + j];
            unsigned int w0 = (unsigned int)v, w1 = (unsigned int)(v >> 32);
            float e0 = __uint_as_float(w0 << 16);
            float e1 = __uint_as_float(w0 & 0xffff0000u);
            float e2 = __uint_as_float(w1 << 16);
            float e3 = __uint_as_float(w1 & 0xffff0000u);
            acc[m][j] += pvv.x * e0 + pvv.y * e1 + pvv.z * e2 + pvv.w * e3;
        }
    }

    // ---- key padding mask ----
    const unsigned int* kmw = (const unsigned int*)(km + b * SEQ);
#pragma unroll
    for (int m = 0; m < 16; ++m) {
        unsigned int mk = kmw[j_s * 64 + m * 4 + lb];
        if (mk & 0x000000ffu) acc[m][0] = -1000.f;
        if (mk & 0x0000ff00u) acc[m][1] = -1000.f;
        if (mk & 0x00ff0000u) acc[m][2] = -1000.f;
        if (mk & 0xff000000u) acc[m][3] = -1000.f;
    }

    // ---- softmax over s (row = t, spread across 4 waves) ----
    float mx = -3.4e38f;
#pragma unroll
    for (int m = 0; m < 16; ++m)
        mx = fmaxf(mx, fmaxf(fmaxf(acc[m][0], acc[m][1]), fmaxf(acc[m][2], acc[m][3])));
    mx = fmaxf(mx, __shfl_xor(mx, 16, 64));
    mx = fmaxf(mx, __shfl_xor(mx, 32, 64));
    if (lane < 16) red_m[lane][j_s] = mx;
    __syncthreads();
    const float fm = fmaxf(fmaxf(red_m[la][0], red_m[la][1]),
                           fmaxf(red_m[la][2], red_m[la][3]));
    float sum = 0.f;
#pragma unroll
    for (int m = 0; m < 16; ++m) {
        acc[m][0] = __expf(acc[m][0] - fm);
        acc[m][1] = __expf(acc[m][1] - fm);
        acc[m][2] = __expf(acc[m][2] - fm);
        acc[m][3] = __expf(acc[m][3] - fm);
        sum += (acc[m][0] + acc[m][1]) + (acc[m][2] + acc[m][3]);
    }
    sum += __shfl_xor(sum, 16, 64);
    sum += __shfl_xor(sum, 32, 64);
    if (lane < 16) red_s[lane][j_s] = sum;
    __syncthreads();
    const float inv = 1.0f / ((red_s[la][0] + red_s[la][1]) + (red_s[la][2] + red_s[la][3]));

    // ---- store (NT: don't pollute L2 where K lives) ----
    float* op = out + ((size_t)hb * SEQ + t) * SEQ;
#pragma unroll
    for (int m = 0; m < 16; ++m) {
        nf4 o;
        o.x = acc[m][0] * inv;
        o.y = acc[m][1] * inv;
        o.z = acc[m][2] * inv;
        o.w = acc[m][3] * inv;
        __builtin_nontemporal_store(o, (nf4*)(op + j_s * 256 + m * 16 + lb * 4));
    }
}

extern "C" void kernel_launch(void* const* d_in, const int* in_sizes, int n_in,
                              void* d_out, int out_size, void* d_ws, size_t ws_size,
                              hipStream_t stream) {
    const float* x       = (const float*)d_in[0];
    const float* pos_emb = (const float*)d_in[1];
    const float* W_in    = (const float*)d_in[2];
    const float* b_in    = (const float*)d_in[3];
    const float* W_pos   = (const float*)d_in[4];
    const unsigned char* km = (const unsigned char*)d_in[5];
    float* out = (float*)d_out;

    char* ws = (char*)d_ws;
    const size_t MB = 1024 * 1024;
    unsigned short* qhi = (unsigned short*)(ws);
    unsigned short* qlo = (unsigned short*)(ws + 4 * MB);
    unsigned short* khi = (unsigned short*)(ws + 8 * MB);
    unsigned short* klo = (unsigned short*)(ws + 12 * MB);
    float*          pws = (float*)(ws + 16 * MB);
    unsigned short* peg = (unsigned short*)(ws + 17 * MB);
    unsigned short* xhi = (unsigned short*)(ws + 18 * MB);
    unsigned short* xlo = (unsigned short*)(ws + 26 * MB);
    unsigned short* whT = (unsigned short*)(ws + 34 * MB);
    unsigned short* wlT = (unsigned short*)(ws + 35 * MB);

    hipLaunchKernelGGL(convx_kernel, dim3(2048), dim3(256), 0, stream, x, xhi, xlo);
    hipLaunchKernelGGL(convw_kernel, dim3(17, 16), dim3(256), 0, stream, W_in, whT, wlT);
    hipLaunchKernelGGL(pe_kernel, dim3(16, 8), dim3(128), 0, stream, pos_emb, W_pos, peg);
    hipLaunchKernelGGL(inproj_kernel, dim3(64, 17), dim3(256), 0, stream,
                       xhi, xlo, whT, wlT, b_in, qhi, qlo, khi, klo, pws);
    hipLaunchKernelGGL(attn_kernel, dim3(4096), dim3(256), 0, stream,
                       qhi, qlo, khi, klo, pws, peg, km, out);
}